// Round 23
// baseline (74.261 us; speedup 1.0000x reference)
//
#include <hip/hip_runtime.h>

typedef _Float16 half8 __attribute__((ext_vector_type(8)));
typedef __fp16  fp16x2 __attribute__((ext_vector_type(2)));
typedef float f32x4 __attribute__((ext_vector_type(4)));

#define HH 6144
#define WW 6144
#define KH 11
#define KW 11
#define OH (HH - KH + 1)   // 6134
#define OW (WW - KW + 1)   // 6134

#define NTH 384            // 6 waves per block
#define BROWS 32           // out rows per block
#define BCOLS 144          // out cols per block (3 strips of 48)
#define SR 42              // staged input rows (32 + 10 halo)
#define SCH 40             // 16B fp32 chunks per row (160 f32; need 155)
#define F_ROWB 640         // fp32 row bytes
#define H_ROWB 320         // fp16 row stride: 16B-aligned; (16n+4h) mod 32 ->
                           // 8 slots x 8 lanes = 2/bank = free
#define A_WAVES 27         // 1728 slots >= 1680 real (pad clamps to last row)
#define B_LDS 13440        // H end (42*320); B in dead F space [13440,20608)
#define LDSB 27648         // A_WAVES*1024 -> 5 blocks/CU, 30 waves (94%)
#define CV_TASKS 840       // 42 rows * 20 col-octs

#define TILES_X 43         // ceil(6134/144)
#define TILES_Y 192
#define NWG (TILES_X * TILES_Y)   // 8256 = 8 * 1032

// ---- prep: compact B table, sigma-permuted slot order (verified r15-r21) ---
__global__ void build_B_kernel(const float* __restrict__ Wt,
                               _Float16* __restrict__ Bc) {
    const int t = (int)blockIdx.x * 256 + (int)threadIdx.x;
    if (t < 448 * 8) {
        const int e  = t & 7;
        const int p  = t >> 3;
        const int kb = p / 40;
        const int sg = p - kb * 40;
        const int s  = (sg % 5) * 8 + sg / 5;
        float v = 0.f;
        if (kb < KH) {
            const int d = s + e - 15;
            if (d >= 0 && d < KW) v = Wt[kb * KW + d];
        }
        Bc[t] = (_Float16)v;
    }
}

union pk2 { fp16x2 h; unsigned int u; };
static __device__ __forceinline__ unsigned int cvt2(float a, float b) {
#if defined(__has_builtin) && __has_builtin(__builtin_amdgcn_cvt_pkrtz)
    pk2 r; r.h = __builtin_amdgcn_cvt_pkrtz(a, b);
#else
    pk2 r; r.h[0] = (__fp16)a; r.h[1] = (__fp16)b;
#endif
    return r.u;
}

__global__ __launch_bounds__(NTH, 7)
void conv2d_dma10_kernel(const float* __restrict__ X,
                         const _Float16* __restrict__ Bc,
                         const float* __restrict__ bias,
                         float* __restrict__ out)
{
    __shared__ __align__(16) char lds[LDSB];

    // XCD-chunked remap (bijective: 8256 % 8 == 0)
    const int bid = (int)blockIdx.x;
    const int sb  = (bid & 7) * (NWG / 8) + (bid >> 3);
    const int txt = sb % TILES_X;
    const int tyt = sb / TILES_X;

    const int x0 = txt * BCOLS;
    const int y0 = tyt * BROWS;
    const int tid = (int)threadIdx.x;
    const int lane = tid & 63;
    const int wv = tid >> 6;        // 0..5
    const int n  = lane & 15;
    const int h  = lane >> 4;
    const int rt = wv & 1;          // row-tile (0,1)
    const int cs = wv >> 1;         // col strip of 48 (0,1,2)
    const float bv = bias[0];

    const bool interior = (txt < TILES_X - 1) && (tyt < TILES_Y - 1);

    // ---------------- stage A: DMA global -> LDS (F region, linear) ---------
    // F slot t (t < 1728): X row r = t/40 (clamped), chunk j = t%40.
    if (interior) {
        #pragma unroll
        for (int k = 0; k < 5; ++k) {
            const int wabs = k * 6 + wv;              // 0..29, wave-uniform
            if (wabs < A_WAVES) {
                char* ldst = lds + wabs * 1024;       // uniform; HW adds lane*16
                const int t = wabs * 64 + lane;
                int r = t / SCH;
                const int j = t - r * SCH;
                if (r > SR - 1) r = SR - 1;           // pad tasks: benign clamp
                const void* src = (const void*)(X + (size_t)(y0 + r) * WW + (x0 + 4 * j));
                __builtin_amdgcn_global_load_lds(
                    (const __attribute__((address_space(1))) void*)src,
                    (__attribute__((address_space(3))) void*)ldst,
                    16, 0, 0);
            }
        }
    } else {
        #pragma unroll 1
        for (int k = 0; k < 5; ++k) {
            const int wabs = k * 6 + wv;
            if (wabs < A_WAVES) {
                const int t = wabs * 64 + lane;
                int r = t / SCH;
                const int j = t - r * SCH;
                if (r > SR - 1) r = SR - 1;
                const int gy = y0 + r;
                const int gx = x0 + 4 * j;
                f32x4 v = {0.f, 0.f, 0.f, 0.f};
                if (gy < HH) {
                    const float* rp = X + (size_t)gy * WW;
                    if (gx + 3 < WW) {
                        v = *reinterpret_cast<const f32x4*>(rp + gx);
                    } else {
                        if (gx + 0 < WW) v[0] = rp[gx + 0];
                        if (gx + 1 < WW) v[1] = rp[gx + 1];
                        if (gx + 2 < WW) v[2] = rp[gx + 2];
                    }
                }
                *reinterpret_cast<f32x4*>(lds + (size_t)t * 16) = v;
            }
        }
    }

    __syncthreads();   // drains A-DMA (vmcnt(0))

    // ---------------- convert pass: fp32 F (640-stride) -> regs -------------
    f32x4 CV[3][2];
    #pragma unroll
    for (int it = 0; it < 3; ++it) {
        const int idx = it * NTH + tid;
        if (idx < CV_TASKS) {
            const int r = idx / 20;
            const int m = idx - r * 20;
            const char* frow = lds + (size_t)r * F_ROWB + m * 32;
            CV[it][0] = *reinterpret_cast<const f32x4*>(frow);
            CV[it][1] = *reinterpret_cast<const f32x4*>(frow + 16);
        }
    }

    __syncthreads();   // ALL F reads done -> F region dead, reusable

    // ---- stage B: DMA sigma-table into dead F space [B_LDS, B_LDS+7168) ----
    if (interior) {
        #pragma unroll
        for (int k = 0; k < 2; ++k) {
            const int wb = k * 6 + wv;
            if (wb < 7) {
                char* ldst = lds + B_LDS + wb * 1024;
                const void* src = (const void*)((const char*)Bc + (size_t)(wb * 64 + lane) * 16);
                __builtin_amdgcn_global_load_lds(
                    (const __attribute__((address_space(1))) void*)src,
                    (__attribute__((address_space(3))) void*)ldst,
                    16, 0, 0);
            }
        }
    } else {
        #pragma unroll
        for (int k = 0; k < 2; ++k) {
            const int wb = k * 6 + wv;
            if (wb < 7) {
                const int t = wb * 64 + lane;
                *reinterpret_cast<uint4*>(lds + B_LDS + (size_t)t * 16) =
                    *reinterpret_cast<const uint4*>((const char*)Bc + (size_t)t * 16);
            }
        }
    }

    // ---- write H rows (stride 320) into [0, 13440) -------------------------
    #pragma unroll
    for (int it = 0; it < 3; ++it) {
        const int idx = it * NTH + tid;
        if (idx < CV_TASKS) {
            const int r = idx / 20;
            const int m = idx - r * 20;
            union { unsigned int u[4]; uint4 q; } fr;
            fr.u[0] = cvt2(CV[it][0][0], CV[it][0][1]);
            fr.u[1] = cvt2(CV[it][0][2], CV[it][0][3]);
            fr.u[2] = cvt2(CV[it][1][0], CV[it][1][1]);
            fr.u[3] = cvt2(CV[it][1][2], CV[it][1][3]);
            *reinterpret_cast<uint4*>(lds + (size_t)r * H_ROWB + m * 16) = fr.q;
        }
    }

    f32x4 acc[3];
    #pragma unroll
    for (int c = 0; c < 3; ++c) acc[c] = (f32x4){bv, bv, bv, bv};

    __syncthreads();   // drains B-DMA + orders H writes

    // ---------------- compute: one b128 per MFMA (fp16) ---------------------
    // A(kb,c) lane(n,h): row 16rt+n+kb, addr = row*320 + 96cs + 32c + 16h
    //   reads beyond real col 154 pair with W=0 (d>=12) and hold finite
    //   converted-X halves (SCH=40 stages 160 real cols) -> no NaN hazard
    // B(kb)   lane(n,h): addr = B_LDS + sigma(8h-n+15)*16 + kb*640
    const int s_log = 8 * h - n + 15;
    const int sig   = (s_log & 7) * 5 + (s_log >> 3);
    const char* abase = lds + (16 * rt + n) * H_ROWB + 96 * cs + 16 * h;
    const char* bbase = lds + B_LDS + sig * 16;
    #pragma unroll
    for (int kb = 0; kb < 11; ++kb) {
        const half8 bf = *reinterpret_cast<const half8*>(bbase + kb * 640);
        const char* arow = abase + kb * H_ROWB;
        #pragma unroll
        for (int c = 0; c < 3; ++c) {
            half8 a = *reinterpret_cast<const half8*>(arow + 32 * c);
            acc[c] = __builtin_amdgcn_mfma_f32_16x16x32_f16(a, bf, acc[c], 0, 0, 0);
        }
    }

    // ---------------- store: out row 16rt+4h+r, col 48cs+16c+n --------------
    const int orow0 = y0 + 16 * rt + 4 * h;
    const int ocol0 = x0 + 48 * cs + n;
    if (interior) {
        #pragma unroll
        for (int r = 0; r < 4; ++r) {
            float* op = out + (size_t)(orow0 + r) * OW + ocol0;
            #pragma unroll
            for (int c = 0; c < 3; ++c)
                op[16 * c] = acc[c][r];
        }
    } else {
        #pragma unroll
        for (int r = 0; r < 4; ++r) {
            if (orow0 + r < OH) {
                float* op = out + (size_t)(orow0 + r) * OW + ocol0;
                #pragma unroll
                for (int c = 0; c < 3; ++c)
                    if (ocol0 + 16 * c < OW) op[16 * c] = acc[c][r];
            }
        }
    }
}

extern "C" void kernel_launch(void* const* d_in, const int* in_sizes, int n_in,
                              void* d_out, int out_size, void* d_ws, size_t ws_size,
                              hipStream_t stream) {
    const float* X    = (const float*)d_in[0];
    const float* Wt   = (const float*)d_in[1];
    const float* bias = (const float*)d_in[2];
    float* out        = (float*)d_out;
    _Float16* Bc      = (_Float16*)d_ws;      // 7168 B

    build_B_kernel<<<dim3(14), dim3(256), 0, stream>>>(Wt, Bc);
    conv2d_dma10_kernel<<<dim3(NWG), dim3(NTH), 0, stream>>>(X, Bc, bias, out);
}

// Round 24
// 67.466 us; speedup vs baseline: 1.1007x; 1.1007x over previous
//
#include <hip/hip_runtime.h>

typedef _Float16 half8 __attribute__((ext_vector_type(8)));
typedef __fp16  fp16x2 __attribute__((ext_vector_type(2)));
typedef float f32x4 __attribute__((ext_vector_type(4)));

#define HH 6144
#define WW 6144
#define KH 11
#define KW 11
#define OH (HH - KH + 1)   // 6134
#define OW (WW - KW + 1)   // 6134

#define NTH 512            // 8 waves per block
#define BROWS 64           // out rows per block (4 row-tiles of 16)
#define BCOLS 96           // out cols per block (2 strips of 48)
#define SR 74              // staged input rows (64 + 10 halo) -> 1.16x (was 1.31x)
#define SCH 28             // 16B fp32 chunks per row (112 f32; need 111)
#define F_ROWB 448         // fp32 row bytes
#define H_ROWB 224         // fp16 row bytes: 16B-aligned; (n*56+h*4) mod 32 hits
                           // each 4-dw offset exactly 8x = conflict-free (dma8-verified)
#define A_WAVES 33         // 2112 slots >= 2072 real (pad clamps to last row)
#define B_LDS 16576        // H end (74*224); B in dead F space [16576,23744)
#define LDSB 33792         // A_WAVES*1024 -> 4 blocks/CU x 8 waves = 32 waves = 100%
#define CV_TASKS 1036      // 74 rows * 14 col-octs

#define TILES_X 64
#define TILES_Y 96
#define NWG (TILES_X * TILES_Y)   // 6144 = 8 * 768

// ---- prep: compact B table, sigma-permuted slot order (verified r15-r22) ---
__global__ void build_B_kernel(const float* __restrict__ Wt,
                               _Float16* __restrict__ Bc) {
    const int t = (int)blockIdx.x * 256 + (int)threadIdx.x;
    if (t < 448 * 8) {
        const int e  = t & 7;
        const int p  = t >> 3;
        const int kb = p / 40;
        const int sg = p - kb * 40;
        const int s  = (sg % 5) * 8 + sg / 5;
        float v = 0.f;
        if (kb < KH) {
            const int d = s + e - 15;
            if (d >= 0 && d < KW) v = Wt[kb * KW + d];
        }
        Bc[t] = (_Float16)v;
    }
}

union pk2 { fp16x2 h; unsigned int u; };
static __device__ __forceinline__ unsigned int cvt2(float a, float b) {
#if defined(__has_builtin) && __has_builtin(__builtin_amdgcn_cvt_pkrtz)
    pk2 r; r.h = __builtin_amdgcn_cvt_pkrtz(a, b);
#else
    pk2 r; r.h[0] = (__fp16)a; r.h[1] = (__fp16)b;
#endif
    return r.u;
}

__global__ __launch_bounds__(NTH, 8)
void conv2d_dma11_kernel(const float* __restrict__ X,
                         const _Float16* __restrict__ Bc,
                         const float* __restrict__ bias,
                         float* __restrict__ out)
{
    __shared__ __align__(16) char lds[LDSB];

    // XCD-chunked remap (bijective: 6144 % 8 == 0)
    const int bid = (int)blockIdx.x;
    const int sb  = (bid & 7) * (NWG / 8) + (bid >> 3);
    const int txt = sb % TILES_X;
    const int tyt = sb / TILES_X;

    const int x0 = txt * BCOLS;
    const int y0 = tyt * BROWS;
    const int tid = (int)threadIdx.x;
    const int lane = tid & 63;
    const int wv = tid >> 6;        // 0..7
    const int n  = lane & 15;
    const int h  = lane >> 4;
    const int rt = wv & 3;          // row-tile (0..3)
    const int cs = wv >> 2;         // col strip of 48 (0,1)
    const float bv = bias[0];

    const bool interior = (txt < TILES_X - 1) && (tyt < TILES_Y - 1);

    // ---------------- stage A: DMA global -> LDS (F region, linear) ---------
    // F slot t (t < 2112): X row r = t/28 (clamped to 73), chunk j = t%28.
    if (interior) {
        #pragma unroll
        for (int k = 0; k < 5; ++k) {
            const int wabs = k * 8 + wv;              // 0..39, wave-uniform
            if (wabs < A_WAVES) {
                char* ldst = lds + wabs * 1024;       // uniform; HW adds lane*16
                const int t = wabs * 64 + lane;
                int r = t / SCH;
                const int j = t - r * SCH;
                if (r > SR - 1) r = SR - 1;           // pad tasks: benign clamp
                const void* src = (const void*)(X + (size_t)(y0 + r) * WW + (x0 + 4 * j));
                __builtin_amdgcn_global_load_lds(
                    (const __attribute__((address_space(1))) void*)src,
                    (__attribute__((address_space(3))) void*)ldst,
                    16, 0, 0);
            }
        }
    } else {
        #pragma unroll 1
        for (int k = 0; k < 5; ++k) {
            const int wabs = k * 8 + wv;
            if (wabs < A_WAVES) {
                const int t = wabs * 64 + lane;
                int r = t / SCH;
                const int j = t - r * SCH;
                if (r > SR - 1) r = SR - 1;
                const int gy = y0 + r;
                const int gx = x0 + 4 * j;
                f32x4 v = {0.f, 0.f, 0.f, 0.f};
                if (gy < HH) {
                    const float* rp = X + (size_t)gy * WW;
                    if (gx + 3 < WW) {
                        v = *reinterpret_cast<const f32x4*>(rp + gx);
                    } else {
                        if (gx + 0 < WW) v[0] = rp[gx + 0];
                        if (gx + 1 < WW) v[1] = rp[gx + 1];
                        if (gx + 2 < WW) v[2] = rp[gx + 2];
                    }
                }
                *reinterpret_cast<f32x4*>(lds + (size_t)t * 16) = v;
            }
        }
    }

    __syncthreads();   // drains A-DMA (vmcnt(0))

    // ---------------- convert pass: fp32 F (448-stride) -> regs -------------
    f32x4 CV[3][2];
    #pragma unroll
    for (int it = 0; it < 3; ++it) {
        const int idx = it * NTH + tid;
        if (idx < CV_TASKS) {
            const int r = idx / 14;
            const int m = idx - r * 14;
            const char* frow = lds + (size_t)r * F_ROWB + m * 32;
            CV[it][0] = *reinterpret_cast<const f32x4*>(frow);
            CV[it][1] = *reinterpret_cast<const f32x4*>(frow + 16);
        }
    }

    __syncthreads();   // ALL F reads done -> F region dead, reusable

    // ---- stage B: DMA sigma-table into dead F space [B_LDS, B_LDS+7168) ----
    if (interior) {
        if (wv < 7) {
            char* ldst = lds + B_LDS + wv * 1024;
            const void* src = (const void*)((const char*)Bc + (size_t)(wv * 64 + lane) * 16);
            __builtin_amdgcn_global_load_lds(
                (const __attribute__((address_space(1))) void*)src,
                (__attribute__((address_space(3))) void*)ldst,
                16, 0, 0);
        }
    } else {
        if (wv < 7) {
            const int t = wv * 64 + lane;
            *reinterpret_cast<uint4*>(lds + B_LDS + (size_t)t * 16) =
                *reinterpret_cast<const uint4*>((const char*)Bc + (size_t)t * 16);
        }
    }

    // ---- write H rows (stride 224) into [0, 16576) -------------------------
    #pragma unroll
    for (int it = 0; it < 3; ++it) {
        const int idx = it * NTH + tid;
        if (idx < CV_TASKS) {
            const int r = idx / 14;
            const int m = idx - r * 14;
            union { unsigned int u[4]; uint4 q; } fr;
            fr.u[0] = cvt2(CV[it][0][0], CV[it][0][1]);
            fr.u[1] = cvt2(CV[it][0][2], CV[it][0][3]);
            fr.u[2] = cvt2(CV[it][1][0], CV[it][1][1]);
            fr.u[3] = cvt2(CV[it][1][2], CV[it][1][3]);
            *reinterpret_cast<uint4*>(lds + (size_t)r * H_ROWB + m * 16) = fr.q;
        }
    }

    f32x4 acc[3];
    #pragma unroll
    for (int c = 0; c < 3; ++c) acc[c] = (f32x4){bv, bv, bv, bv};

    __syncthreads();   // drains B-DMA + orders H writes

    // ---------------- compute: one b128 per MFMA (fp16) ---------------------
    // A(kb,c) lane(n,h): row 16rt+n+kb (max 63+10=73 < 74), addr = row*224
    //   + 96cs + 32c + 16h  (16B-aligned, conflict-free floor — dma8-verified)
    // B(kb)   lane(n,h): addr = B_LDS + sigma(8h-n+15)*16 + kb*640
    const int s_log = 8 * h - n + 15;
    const int sig   = (s_log & 7) * 5 + (s_log >> 3);
    const char* abase = lds + (16 * rt + n) * H_ROWB + 96 * cs + 16 * h;
    const char* bbase = lds + B_LDS + sig * 16;
    #pragma unroll
    for (int kb = 0; kb < 11; ++kb) {
        const half8 bf = *reinterpret_cast<const half8*>(bbase + kb * 640);
        const char* arow = abase + kb * H_ROWB;
        #pragma unroll
        for (int c = 0; c < 3; ++c) {
            half8 a = *reinterpret_cast<const half8*>(arow + 32 * c);
            acc[c] = __builtin_amdgcn_mfma_f32_16x16x32_f16(a, bf, acc[c], 0, 0, 0);
        }
    }

    // ---------------- store: out row y0+16rt+4h+r, col x0+48cs+16c+n --------
    const int orow0 = y0 + 16 * rt + 4 * h;
    const int ocol0 = x0 + 48 * cs + n;
    if (interior) {
        #pragma unroll
        for (int r = 0; r < 4; ++r) {
            float* op = out + (size_t)(orow0 + r) * OW + ocol0;
            #pragma unroll
            for (int c = 0; c < 3; ++c)
                op[16 * c] = acc[c][r];
        }
    } else {
        #pragma unroll
        for (int r = 0; r < 4; ++r) {
            if (orow0 + r < OH) {
                float* op = out + (size_t)(orow0 + r) * OW + ocol0;
                #pragma unroll
                for (int c = 0; c < 3; ++c)
                    if (ocol0 + 16 * c < OW) op[16 * c] = acc[c][r];
            }
        }
    }
}

extern "C" void kernel_launch(void* const* d_in, const int* in_sizes, int n_in,
                              void* d_out, int out_size, void* d_ws, size_t ws_size,
                              hipStream_t stream) {
    const float* X    = (const float*)d_in[0];
    const float* Wt   = (const float*)d_in[1];
    const float* bias = (const float*)d_in[2];
    float* out        = (float*)d_out;
    _Float16* Bc      = (_Float16*)d_ws;      // 7168 B

    build_B_kernel<<<dim3(14), dim3(256), 0, stream>>>(Wt, Bc);
    conv2d_dma11_kernel<<<dim3(NWG), dim3(NTH), 0, stream>>>(X, Bc, bias, out);
}